// Round 3
// baseline (229.125 us; speedup 1.0000x reference)
//
#include <hip/hip_runtime.h>
#include <cstdint>
#include <cstddef>

#define B_  16
#define N_  512
#define D_  256
#define H_  8
#define DK_ 32
// Round 11: fix qkv_st's register-starved serialization (VGPR_Count=32 -> all
// loads serialized, 66us for ~15us of work).
//  1) prep_w (256 blk): W -> bf16 (unchanged).
//  2) pre_kernel (1024 blk x 512 thr, launch_bounds(512,4) -> <=128 VGPR,
//     2 blk/CU): role-split co-scheduling. Even blocks: ST build (pure HBM
//     streaming, 12 loads batched into named regs -> full MLP). Odd blocks:
//     QKV projection for 16 tokens, z-loop fully interleaved (3 A streams +
//     6 W streams + 6 acc chains per k-step -> ILP instead of serial chains).
//     Streaming waves and MFMA waves co-resident on each CU overlap pipes.
//  3) attn_kernel: unchanged (deferred softmax, 2 blk/CU).

#define QKV_ELEMS 2097152   // B*N*D

__device__ __align__(16) unsigned short g_Qb[QKV_ELEMS];   // [B,H,N,DK] bf16
__device__ __align__(16) unsigned short g_Kb[QKV_ELEMS];   // [B,H,N,DK] bf16
__device__ __align__(16) unsigned short g_VT[QKV_ELEMS];   // [B,H,tokblk,DK,tok32] bf16
__device__ __align__(16) unsigned short g_WqB[D_*D_];      // Wq bf16 [n][k]
__device__ __align__(16) unsigned short g_WkB[D_*D_];      // Wk bf16 [n][k]
__device__ __align__(16) unsigned short g_WvB[D_*D_];      // Wv bf16 [n][k]
__device__ __align__(16) unsigned short g_WoB[D_*D_];      // Wo bf16 [k>>5][n][k&31]
__device__ __align__(16) unsigned short g_ST[B_*N_*N_];    // blended dist/adj bf16 [b][q][k]

typedef short v8s __attribute__((ext_vector_type(8)));
typedef float v4f __attribute__((ext_vector_type(4)));

__device__ __forceinline__ unsigned short f2b(float f){
  unsigned int x;
  __builtin_memcpy(&x, &f, 4);
  x = x + 0x7FFFu + ((x >> 16) & 1u);   // round-to-nearest-even
  return (unsigned short)(x >> 16);
}
__device__ __forceinline__ v8s pack8(const float4 a, const float4 b){
  v8s o;
  o[0]=(short)f2b(a.x); o[1]=(short)f2b(a.y); o[2]=(short)f2b(a.z); o[3]=(short)f2b(a.w);
  o[4]=(short)f2b(b.x); o[5]=(short)f2b(b.y); o[6]=(short)f2b(b.z); o[7]=(short)f2b(b.w);
  return o;
}

// ---------------------------------------------------------------------------
// Dispatch 0: weight conversion. 256 blocks x 256 thr, 4 elems/thread.
// ---------------------------------------------------------------------------
__global__ __launch_bounds__(256) void prep_w(
    const float* __restrict__ Wq, const float* __restrict__ Wk,
    const float* __restrict__ Wv, const float* __restrict__ Wo)
{
  const int bid = blockIdx.x;
  const int z = bid >> 6;                     // 0:Wq 1:Wk 2:Wv 3:Wo
  const int i = ((bid & 63)*256 + (int)threadIdx.x)*4;
  const float* src = (z==0)?Wq:(z==1)?Wk:(z==2)?Wv:Wo;
  const float4 u = *reinterpret_cast<const float4*>(src + i);
  ushort4 o4;
  o4.x = f2b(u.x); o4.y = f2b(u.y); o4.z = f2b(u.z); o4.w = f2b(u.w);
  if (z < 3){
    unsigned short* dst = (z==0)?g_WqB:(z==1)?g_WkB:g_WvB;
    *reinterpret_cast<ushort4*>(dst + i) = o4;
  } else {
    const int n = i >> 8, k = i & 255;
    *reinterpret_cast<ushort4*>(g_WoB + ((size_t)(k >> 5))*8192 + (size_t)n*32 + (k & 31)) = o4;
  }
}

// ---------------------------------------------------------------------------
// Dispatch 1: role-split. Even blocks: ST build. Odd blocks: QKV projection.
// 1024 blocks x 512 thr; (b,qt) = ((bid>>1)&15, bid>>5).
// ---------------------------------------------------------------------------
__global__ __launch_bounds__(512, 4) void pre_kernel(
    const float* __restrict__ query, const float* __restrict__ key_,
    const float* __restrict__ value, const float* __restrict__ dist,
    const float* __restrict__ adjm,  const int* __restrict__ mask,
    const float* __restrict__ bq, const float* __restrict__ bk,
    const float* __restrict__ bv)
{
  const int bid = blockIdx.x;
  const int role = bid & 1;
  const int b  = (bid >> 1) & 15;             // same-b pairs -> same XCD
  const int qt = bid >> 5;
  const int q0 = qt*16;
  const int t  = threadIdx.x;

  if (role == 0){
    // ---- ST build: 16 rows x 512 k; thread = (row, 16-k segment). ----
    // All 12 loads issued into named regs before any compute (MLP).
    const int row = t >> 5, seg = t & 31;
    const size_t roff = ((size_t)(b*N_ + q0 + row))*N_ + seg*16;
    const float* dp = dist + roff;
    const float* ap = adjm + roff;
    const int*   mp = mask + b*N_ + seg*16;
    const float4 d0 = reinterpret_cast<const float4*>(dp)[0];
    const float4 d1 = reinterpret_cast<const float4*>(dp)[1];
    const float4 d2 = reinterpret_cast<const float4*>(dp)[2];
    const float4 d3 = reinterpret_cast<const float4*>(dp)[3];
    const float4 a0 = reinterpret_cast<const float4*>(ap)[0];
    const float4 a1 = reinterpret_cast<const float4*>(ap)[1];
    const float4 a2 = reinterpret_cast<const float4*>(ap)[2];
    const float4 a3 = reinterpret_cast<const float4*>(ap)[3];
    const int4   m0 = reinterpret_cast<const int4*>(mp)[0];
    const int4   m1 = reinterpret_cast<const int4*>(mp)[1];
    const int4   m2 = reinterpret_cast<const int4*>(mp)[2];
    const int4   m3 = reinterpret_cast<const int4*>(mp)[3];

    float ev[16], av[16];
    #define ST_STEP(i, d4, a4, m4) \
      ev[i+0] = m4.x ? __expf(-d4.x) : 0.f;  av[i+0] = a4.x; \
      ev[i+1] = m4.y ? __expf(-d4.y) : 0.f;  av[i+1] = a4.y; \
      ev[i+2] = m4.z ? __expf(-d4.z) : 0.f;  av[i+2] = a4.z; \
      ev[i+3] = m4.w ? __expf(-d4.w) : 0.f;  av[i+3] = a4.w;
    ST_STEP(0,  d0, a0, m0)
    ST_STEP(4,  d1, a1, m1)
    ST_STEP(8,  d2, a2, m2)
    ST_STEP(12, d3, a3, m3)
    #undef ST_STEP
    float lz = 0.f, la = 0.f;
    #pragma unroll
    for (int i = 0; i < 16; ++i){ lz += ev[i]; la += av[i]; }
    #pragma unroll
    for (int o = 1; o < 32; o <<= 1){   // 32 lanes share a row (bits 0..4)
      lz += __shfl_xor(lz, o, 64);
      la += __shfl_xor(la, o, 64);
    }
    const float c0 = (lz > 0.f) ? 0.3f / lz : 0.f;
    const float c1 = 0.4f / (la + 1e-6f);
    v8s s0, s1;
    #pragma unroll
    for (int i = 0; i < 8; ++i){
      s0[i] = (short)f2b(ev[i]*c0   + av[i]*c1);
      s1[i] = (short)f2b(ev[8+i]*c0 + av[8+i]*c1);
    }
    *reinterpret_cast<v8s*>(g_ST + roff)     = s0;
    *reinterpret_cast<v8s*>(g_ST + roff + 8) = s1;
    return;
  }

  // ---- QKV GEMM for 16 tokens: M=16, N=256, K=256, all 3 z interleaved ----
  const int w = t >> 6, lane = t & 63, kl = lane & 15, quad = lane >> 4;
  const size_t arow = ((size_t)(b*N_ + q0 + kl))*256;   // A row for frag (m=kl)
  const int n0 = w*32;
  const v4f vz = {0.f,0.f,0.f,0.f};

  const float* qp = query + arow;
  const float* kp = key_  + arow;
  const float* vp = value + arow;
  const unsigned short* wq0p = g_WqB + (size_t)(n0      + kl)*256;
  const unsigned short* wq1p = g_WqB + (size_t)(n0 + 16 + kl)*256;
  const unsigned short* wk0p = g_WkB + (size_t)(n0      + kl)*256;
  const unsigned short* wk1p = g_WkB + (size_t)(n0 + 16 + kl)*256;
  const unsigned short* wv0p = g_WvB + (size_t)(n0      + kl)*256;
  const unsigned short* wv1p = g_WvB + (size_t)(n0 + 16 + kl)*256;

  v4f cq0 = vz, cq1 = vz, ck0 = vz, ck1 = vz, cv0 = vz, cv1 = vz;
  #pragma unroll
  for (int k0 = 0; k0 < 256; k0 += 32){
    const int o = k0 + quad*8;
    const float4 qa = *reinterpret_cast<const float4*>(qp + o);
    const float4 qb = *reinterpret_cast<const float4*>(qp + o + 4);
    const float4 ka = *reinterpret_cast<const float4*>(kp + o);
    const float4 kb = *reinterpret_cast<const float4*>(kp + o + 4);
    const float4 va = *reinterpret_cast<const float4*>(vp + o);
    const float4 vb = *reinterpret_cast<const float4*>(vp + o + 4);
    const v8s wq0 = *reinterpret_cast<const v8s*>(wq0p + o);
    const v8s wq1 = *reinterpret_cast<const v8s*>(wq1p + o);
    const v8s wk0 = *reinterpret_cast<const v8s*>(wk0p + o);
    const v8s wk1 = *reinterpret_cast<const v8s*>(wk1p + o);
    const v8s wv0 = *reinterpret_cast<const v8s*>(wv0p + o);
    const v8s wv1 = *reinterpret_cast<const v8s*>(wv1p + o);
    const v8s fq = pack8(qa, qb);
    const v8s fk = pack8(ka, kb);
    const v8s fv = pack8(va, vb);
    // Q/K swapped operands: D[n][tok] -> ushort4 stores along n.
    cq0 = __builtin_amdgcn_mfma_f32_16x16x32_bf16(wq0, fq, cq0, 0, 0, 0);
    cq1 = __builtin_amdgcn_mfma_f32_16x16x32_bf16(wq1, fq, cq1, 0, 0, 0);
    ck0 = __builtin_amdgcn_mfma_f32_16x16x32_bf16(wk0, fk, ck0, 0, 0, 0);
    ck1 = __builtin_amdgcn_mfma_f32_16x16x32_bf16(wk1, fk, ck1, 0, 0, 0);
    // V: D[tok][n] -> ushort4 stores along tok (interleaved layout).
    cv0 = __builtin_amdgcn_mfma_f32_16x16x32_bf16(fv, wv0, cv0, 0, 0, 0);
    cv1 = __builtin_amdgcn_mfma_f32_16x16x32_bf16(fv, wv1, cv1, 0, 0, 0);
  }

  // Q/K store: lane holds tok = q0+kl, n = n0 + nb*16 + quad*4 + r
  #pragma unroll
  for (int nb = 0; nb < 2; ++nb){
    const v4f aQ = nb ? cq1 : cq0;
    const v4f aK = nb ? ck1 : ck0;
    const int nn = n0 + nb*16 + quad*4;
    const float4 bq4 = *reinterpret_cast<const float4*>(bq + nn);
    const float4 bk4 = *reinterpret_cast<const float4*>(bk + nn);
    ushort4 oq, ok;
    oq.x=f2b(aQ[0]+bq4.x); oq.y=f2b(aQ[1]+bq4.y); oq.z=f2b(aQ[2]+bq4.z); oq.w=f2b(aQ[3]+bq4.w);
    ok.x=f2b(aK[0]+bk4.x); ok.y=f2b(aK[1]+bk4.y); ok.z=f2b(aK[2]+bk4.z); ok.w=f2b(aK[3]+bk4.w);
    const size_t base = (((size_t)(b*H_+w))*N_ + q0 + kl)*DK_ + (nn & 31);
    *reinterpret_cast<ushort4*>(g_Qb + base) = oq;
    *reinterpret_cast<ushort4*>(g_Kb + base) = ok;
  }
  // V store: lane holds dk = nb*16+kl, tok = q0 + quad*4 + r
  #pragma unroll
  for (int nb = 0; nb < 2; ++nb){
    const v4f aV = nb ? cv1 : cv0;
    const float bias = bv[n0 + nb*16 + kl];
    ushort4 ov;
    ov.x=f2b(aV[0]+bias); ov.y=f2b(aV[1]+bias); ov.z=f2b(aV[2]+bias); ov.w=f2b(aV[3]+bias);
    *reinterpret_cast<ushort4*>(g_VT + (((size_t)(b*H_+w))*16 + (qt>>1))*1024
        + (size_t)(nb*16+kl)*32 + (qt&1)*16 + quad*4) = ov;
  }
}

// ---------------------------------------------------------------------------
// Dispatch 2: attention. 512 thr = 8 waves = 8 heads; one (b,qtile).
// k chunked 4x128, deferred softmax normalization -> <=128 regs -> 2 blocks/CU.
// ---------------------------------------------------------------------------
__global__ __launch_bounds__(512, 4) void attn_kernel(
    const int* __restrict__ mask, const float* __restrict__ bo,
    float* __restrict__ out)
{
  __shared__ unsigned short STl[16*520];    // 16.6 KB  ST[qrow][k] bf16 (padded)
  __shared__ unsigned short Pl[8*16*40];    // 10.2 KB  per-wave P chunk
  __shared__ unsigned short Xl[16*272];     //  8.7 KB  X[qrow][n] bf16
  const int bid = blockIdx.x;
  const int b  = bid & 15;                  // same-b -> same XCD (K/V L2 reuse)
  const int qt = bid >> 4;
  const int q0 = qt*16;
  const int t  = threadIdx.x;
  const int w  = t >> 6, lane = t & 63;
  const int kl = lane & 15, quad = lane >> 4;

  // ---- stage precomputed ST tile (16KB bf16, L3-hot) into padded LDS ----
  {
    const int row = t >> 5;                 // 16 rows, 32 thr each
    const int c16 = (t & 31) * 16;
    const unsigned short* src = g_ST + ((size_t)(b*N_ + q0 + row))*N_ + c16;
    *reinterpret_cast<v8s*>(&STl[row*520 + c16])     = *reinterpret_cast<const v8s*>(src);
    *reinterpret_cast<v8s*>(&STl[row*520 + c16 + 8]) = *reinterpret_cast<const v8s*>(src + 8);
  }

  const int h = w;
  const size_t bh = (size_t)b*H_ + h;
  const float scale = 0.17677669529663687f;   // 1/sqrt(32)
  const unsigned short* Qp = g_Qb + (bh*N_ + q0)*DK_;
  const unsigned short* Kp = g_Kb + bh*N_*DK_;
  const unsigned short* Vp = g_VT + bh*(size_t)(N_*DK_);
  unsigned short* Plw = Pl + w*640;           // 16x40 per wave
  const int* mrow = mask + b*N_;
  const v8s aq = *reinterpret_cast<const v8s*>(Qp + (size_t)kl*DK_ + quad*8);
  const v4f vz = {0.f, 0.f, 0.f, 0.f};

  v4f oA0 = vz, oA1 = vz;     // attention PV (unnormalized)
  v4f oS0 = vz, oS1 = vz;     // ST PV (pre-scaled)
  float lsum[4] = {0.f, 0.f, 0.f, 0.f};

  __syncthreads();            // STl visible to all waves

  #pragma unroll 1
  for (int ch = 0; ch < 4; ++ch){
    const int k0 = ch*128;
    v4f acc[8];
    #pragma unroll
    for (int kb = 0; kb < 8; ++kb){
      const v8s bk = *reinterpret_cast<const v8s*>(Kp + (size_t)(k0 + kb*16 + kl)*DK_ + quad*8);
      acc[kb] = __builtin_amdgcn_mfma_f32_16x16x32_bf16(aq, bk, vz, 0, 0, 0);
    }
    #pragma unroll
    for (int kb = 0; kb < 8; ++kb){
      const bool valid = (mrow[k0 + kb*16 + kl] != 0);
      #pragma unroll
      for (int r = 0; r < 4; ++r){
        const float e = valid ? __expf(acc[kb][r]*scale) : 0.f;
        acc[kb][r] = e;               // raw exp; normalize at the end
        lsum[r] += e;
      }
    }
    #pragma unroll
    for (int cc = 0; cc < 4; ++cc){
      #pragma unroll
      for (int r = 0; r < 4; ++r){
        Plw[(quad*4 + r)*40 + kl]      = f2b(acc[2*cc    ][r]);
        Plw[(quad*4 + r)*40 + 16 + kl] = f2b(acc[2*cc + 1][r]);
      }
      const int kk = k0 + cc*32;
      // wave-private region: same-wave write->read ordered via lgkmcnt
      const v8s bp  = *reinterpret_cast<const v8s*>(&Plw[kl*40 + quad*8]);
      const v8s bst = *reinterpret_cast<const v8s*>(&STl[kl*520 + kk + quad*8]);
      const v8s av0 = *reinterpret_cast<const v8s*>(Vp + (size_t)(kk + kl)*32 + quad*8);
      const v8s av1 = *reinterpret_cast<const v8s*>(Vp + (size_t)(kk + 16 + kl)*32 + quad*8);
      oA0 = __builtin_amdgcn_mfma_f32_16x16x32_bf16(av0, bp,  oA0, 0, 0, 0);
      oS0 = __builtin_amdgcn_mfma_f32_16x16x32_bf16(av0, bst, oS0, 0, 0, 0);
      oA1 = __builtin_amdgcn_mfma_f32_16x16x32_bf16(av1, bp,  oA1, 0, 0, 0);
      oS1 = __builtin_amdgcn_mfma_f32_16x16x32_bf16(av1, bst, oS1, 0, 0, 0);
    }
  }

  // softmax denominators: lsum[r] = full-row sum for q = quad*4+r
  #pragma unroll
  for (int r = 0; r < 4; ++r)
    #pragma unroll
    for (int o = 1; o < 16; o <<= 1) lsum[r] += __shfl_xor(lsum[r], o, 64);
  // redistribute: this lane's O columns are q = kl; fetch lsum[kl&3] from quad kl>>2
  const float s01 = (kl & 1) ? lsum[1] : lsum[0];
  const float s23 = (kl & 1) ? lsum[3] : lsum[2];
  const float sv  = (kl & 2) ? s23 : s01;
  float inv = __shfl(sv, ((kl >> 2) << 4) | (kl & 3), 64);
  inv = (inv > 0.f) ? 0.3f / inv : 0.f;

  // X[qrow=kl][n = h*32 + d'] bf16 into LDS (lane holds O^T[d'][q=kl])
  unsigned short* xr = Xl + kl*272 + h*32;
  #pragma unroll
  for (int r = 0; r < 4; ++r){
    xr[     quad*4 + r] = f2b(oA0[r]*inv + oS0[r]);
    xr[16 + quad*4 + r] = f2b(oA1[r]*inv + oS1[r]);
  }
  __syncthreads();

  // ---- Phase C: out = X @ Wo^T + bo, wave w -> n in [w*32, w*32+32) ----
  {
    const int n0 = w*32;
    v4f a2[2];
    a2[0] = vz; a2[1] = vz;
    #pragma unroll
    for (int k0 = 0; k0 < 256; k0 += 32){
      const v8s af = *reinterpret_cast<const v8s*>(&Xl[kl*272 + k0 + quad*8]);
      #pragma unroll
      for (int nb = 0; nb < 2; ++nb){
        const v8s wf = *reinterpret_cast<const v8s*>(
            g_WoB + (size_t)(k0 >> 5)*8192 + (size_t)(n0 + nb*16 + kl)*32 + quad*8);
        a2[nb] = __builtin_amdgcn_mfma_f32_16x16x32_bf16(af, wf, a2[nb], 0, 0, 0);
      }
    }
    #pragma unroll
    for (int nb = 0; nb < 2; ++nb){
      const int n = n0 + nb*16 + kl;
      const float bias = bo[n];
      #pragma unroll
      for (int r = 0; r < 4; ++r)
        out[((size_t)(b*N_ + q0 + quad*4 + r))*256 + n] = a2[nb][r] + bias;
    }
  }
}

extern "C" void kernel_launch(void* const* d_in, const int* in_sizes, int n_in,
                              void* d_out, int out_size, void* d_ws, size_t ws_size,
                              hipStream_t stream)
{
  const float* query = (const float*)d_in[0];
  const float* key_  = (const float*)d_in[1];
  const float* value = (const float*)d_in[2];
  const float* adjm  = (const float*)d_in[3];
  const float* dist  = (const float*)d_in[4];
  // d_in[5] = edges_att (unused)
  const int*   mask  = (const int*)d_in[6];
  const float* Wq = (const float*)d_in[7];  const float* bq = (const float*)d_in[8];
  const float* Wk = (const float*)d_in[9];  const float* bk = (const float*)d_in[10];
  const float* Wv = (const float*)d_in[11]; const float* bv = (const float*)d_in[12];
  const float* Wo = (const float*)d_in[13]; const float* bo = (const float*)d_in[14];

  prep_w<<<256, 256, 0, stream>>>(Wq, Wk, Wv, Wo);
  pre_kernel<<<1024, 512, 0, stream>>>(query, key_, value, dist, adjm, mask,
                                       bq, bk, bv);
  attn_kernel<<<512, 512, 0, stream>>>(mask, bo, (float*)d_out);
}

// Round 4
// 165.045 us; speedup vs baseline: 1.3883x; 1.3883x over previous
//
#include <hip/hip_runtime.h>
#include <cstdint>
#include <cstddef>

#define B_  16
#define N_  512
#define D_  256
#define H_  8
#define DK_ 32
// Round 12: revert to known-good structures, surgically fixed.
// Rounds 10/11 post-mortem: the no-LDS reg-only GEMM compiles to a 32-VGPR
// serialized schedule (2x regression) regardless of source-level ILP.
// Known-good: round-1 LDS-staged GEMM (VGPR 84, MFMA issues properly).
//  1) prep_w (256 blk): Wq/Wk/Wv -> flat bf16, Wo -> tiled bf16. ~2us.
//  2) st_kernel (512 blk x 512 thr, no LDS): dist/adj softmax+blend -> g_ST.
//     Standalone => full occupancy (was trapped under the GEMM's 33.8KB LDS).
//  3) qkv_gemm (1536 blk x 256 thr): round-1 GEMM branch, W staged from
//     PRE-CONVERTED bf16 (removes per-block 64KB fp32 W refetch + convert).
//  4) attn_kernel: unchanged (deferred softmax, 2 blk/CU).

#define QKV_ELEMS 2097152   // B*N*D

__device__ __align__(16) unsigned short g_Qb[QKV_ELEMS];   // [B,H,N,DK] bf16
__device__ __align__(16) unsigned short g_Kb[QKV_ELEMS];   // [B,H,N,DK] bf16
__device__ __align__(16) unsigned short g_VT[QKV_ELEMS];   // [B,H,tokblk,DK,tok32] bf16
__device__ __align__(16) unsigned short g_WqB[D_*D_];      // Wq bf16 [n][k]
__device__ __align__(16) unsigned short g_WkB[D_*D_];      // Wk bf16 [n][k]
__device__ __align__(16) unsigned short g_WvB[D_*D_];      // Wv bf16 [n][k]
__device__ __align__(16) unsigned short g_WoB[D_*D_];      // Wo bf16 [k>>5][n][k&31]
__device__ __align__(16) unsigned short g_ST[B_*N_*N_];    // blended dist/adj bf16 [b][q][k]

typedef short v8s __attribute__((ext_vector_type(8)));
typedef float v4f __attribute__((ext_vector_type(4)));

__device__ __forceinline__ unsigned short f2b(float f){
  unsigned int x;
  __builtin_memcpy(&x, &f, 4);
  x = x + 0x7FFFu + ((x >> 16) & 1u);   // round-to-nearest-even
  return (unsigned short)(x >> 16);
}
__device__ __forceinline__ v8s pack8(const float4 a, const float4 b){
  v8s o;
  o[0]=(short)f2b(a.x); o[1]=(short)f2b(a.y); o[2]=(short)f2b(a.z); o[3]=(short)f2b(a.w);
  o[4]=(short)f2b(b.x); o[5]=(short)f2b(b.y); o[6]=(short)f2b(b.z); o[7]=(short)f2b(b.w);
  return o;
}

// ---------------------------------------------------------------------------
// Dispatch 0: weight conversion. 256 blocks x 256 thr, 4 elems/thread.
// ---------------------------------------------------------------------------
__global__ __launch_bounds__(256) void prep_w(
    const float* __restrict__ Wq, const float* __restrict__ Wk,
    const float* __restrict__ Wv, const float* __restrict__ Wo)
{
  const int bid = blockIdx.x;
  const int z = bid >> 6;                     // 0:Wq 1:Wk 2:Wv 3:Wo
  const int i = ((bid & 63)*256 + (int)threadIdx.x)*4;
  const float* src = (z==0)?Wq:(z==1)?Wk:(z==2)?Wv:Wo;
  const float4 u = *reinterpret_cast<const float4*>(src + i);
  ushort4 o4;
  o4.x = f2b(u.x); o4.y = f2b(u.y); o4.z = f2b(u.z); o4.w = f2b(u.w);
  if (z < 3){
    unsigned short* dst = (z==0)?g_WqB:(z==1)?g_WkB:g_WvB;
    *reinterpret_cast<ushort4*>(dst + i) = o4;
  } else {
    const int n = i >> 8, k = i & 255;
    *reinterpret_cast<ushort4*>(g_WoB + ((size_t)(k >> 5))*8192 + (size_t)n*32 + (k & 31)) = o4;
  }
}

// ---------------------------------------------------------------------------
// Dispatch 1: ST build (standalone streaming). 512 blocks x 512 thr, no LDS.
// Block (b,qt): 16 q-rows x 512 k. Thread = (row, 16-k segment).
// ---------------------------------------------------------------------------
__global__ __launch_bounds__(512) void st_kernel(
    const float* __restrict__ dist, const float* __restrict__ adjm,
    const int* __restrict__ mask)
{
  const int bid = blockIdx.x;
  const int b = bid & 15, qt = bid >> 4, q0 = qt*16;   // same-b -> same XCD
  const int t = threadIdx.x;
  const int row = t >> 5, seg = t & 31;
  const size_t roff = ((size_t)(b*N_ + q0 + row))*N_ + seg*16;
  const float* dp = dist + roff;
  const float* ap = adjm + roff;
  const int*   mp = mask + b*N_ + seg*16;
  // all 12 loads issued back-to-back (MLP)
  const float4 d0 = reinterpret_cast<const float4*>(dp)[0];
  const float4 d1 = reinterpret_cast<const float4*>(dp)[1];
  const float4 d2 = reinterpret_cast<const float4*>(dp)[2];
  const float4 d3 = reinterpret_cast<const float4*>(dp)[3];
  const float4 a0 = reinterpret_cast<const float4*>(ap)[0];
  const float4 a1 = reinterpret_cast<const float4*>(ap)[1];
  const float4 a2 = reinterpret_cast<const float4*>(ap)[2];
  const float4 a3 = reinterpret_cast<const float4*>(ap)[3];
  const int4   m0 = reinterpret_cast<const int4*>(mp)[0];
  const int4   m1 = reinterpret_cast<const int4*>(mp)[1];
  const int4   m2 = reinterpret_cast<const int4*>(mp)[2];
  const int4   m3 = reinterpret_cast<const int4*>(mp)[3];

  float ev[16], av[16];
  #define ST_STEP(i, d4, a4, m4) \
    ev[i+0] = m4.x ? __expf(-d4.x) : 0.f;  av[i+0] = a4.x; \
    ev[i+1] = m4.y ? __expf(-d4.y) : 0.f;  av[i+1] = a4.y; \
    ev[i+2] = m4.z ? __expf(-d4.z) : 0.f;  av[i+2] = a4.z; \
    ev[i+3] = m4.w ? __expf(-d4.w) : 0.f;  av[i+3] = a4.w;
  ST_STEP(0,  d0, a0, m0)
  ST_STEP(4,  d1, a1, m1)
  ST_STEP(8,  d2, a2, m2)
  ST_STEP(12, d3, a3, m3)
  #undef ST_STEP
  float lz = 0.f, la = 0.f;
  #pragma unroll
  for (int i = 0; i < 16; ++i){ lz += ev[i]; la += av[i]; }
  #pragma unroll
  for (int o = 1; o < 32; o <<= 1){   // 32 lanes share a row (bits 0..4)
    lz += __shfl_xor(lz, o, 64);
    la += __shfl_xor(la, o, 64);
  }
  const float c0 = (lz > 0.f) ? 0.3f / lz : 0.f;
  const float c1 = 0.4f / (la + 1e-6f);
  v8s s0, s1;
  #pragma unroll
  for (int i = 0; i < 8; ++i){
    s0[i] = (short)f2b(ev[i]*c0   + av[i]*c1);
    s1[i] = (short)f2b(ev[8+i]*c0 + av[8+i]*c1);
  }
  *reinterpret_cast<v8s*>(g_ST + roff)     = s0;
  *reinterpret_cast<v8s*>(g_ST + roff + 8) = s1;
}

// ---------------------------------------------------------------------------
// Dispatch 2: QKV GEMM (round-1 proven structure, bf16 W source).
// C[m][n] = sum_k A[m][k]*W[n][k] + b[n], M=8192, N=K=256.
// block = 64m x 64n (4 waves x 16 m-rows); W tile staged bf16 -> LDS.
// z==2 (V): operands swapped -> D[n][tok] -> tile-interleaved store.
// ---------------------------------------------------------------------------
__global__ __launch_bounds__(256) void qkv_gemm(
    const float* __restrict__ query, const float* __restrict__ key_,
    const float* __restrict__ value,
    const float* __restrict__ bq, const float* __restrict__ bk,
    const float* __restrict__ bv)
{
  __shared__ unsigned short Wl[64*264];   // 33.8 KB
  const int bid = blockIdx.x;
  const int t   = threadIdx.x;
  const int z  = bid >> 9;                 // 0:Q 1:K 2:V
  const int rr = bid & 511;
  const int mt = rr >> 2, nt = rr & 3;     // nt fastest: 4 consecutive blocks share A tile
  const float* Ap = (z==0) ? query : (z==1) ? key_ : value;
  const unsigned short* WB = (z==0) ? g_WqB : (z==1) ? g_WkB : g_WvB;
  const float* bp = (z==0) ? bq : (z==1) ? bk : bv;
  const int w = t >> 6, lane = t & 63, kl = lane & 15, quad = lane >> 4;
  const int m0 = mt*64 + w*16;
  const int n0 = nt*64;

  {   // stage bf16 W tile [n0..n0+63][0..255] (no conversion needed)
    const int row = t >> 2;
    const int ks  = (t & 3) * 64;
    const unsigned short* src = WB + (size_t)(n0+row)*256 + ks;
    unsigned short* dst = Wl + row*264 + ks;
    #pragma unroll
    for (int u = 0; u < 8; ++u)
      *reinterpret_cast<v8s*>(dst + u*8) = *reinterpret_cast<const v8s*>(src + u*8);
  }
  __syncthreads();

  v4f acc[4];
  #pragma unroll
  for (int nb = 0; nb < 4; ++nb) acc[nb] = (v4f){0.f,0.f,0.f,0.f};
  const int arow = m0 + kl;

  if (z == 2){
    #pragma unroll
    for (int k0 = 0; k0 < 256; k0 += 32){
      const float* ap = Ap + (size_t)arow*256 + k0 + quad*8;
      const v8s af = pack8(reinterpret_cast<const float4*>(ap)[0],
                           reinterpret_cast<const float4*>(ap)[1]);
      #pragma unroll
      for (int nb = 0; nb < 4; ++nb){
        const v8s wf = *reinterpret_cast<const v8s*>(&Wl[(nb*16+kl)*264 + k0 + quad*8]);
        acc[nb] = __builtin_amdgcn_mfma_f32_16x16x32_bf16(wf, af, acc[nb], 0, 0, 0);
      }
    }
    // D[n][tok]; tile-interleaved store: [bb,h, tokblk, dk, tok&31]
    const int tok = m0 + kl, bb = tok >> 9, nr = tok & 511;
    #pragma unroll
    for (int nb = 0; nb < 4; ++nb)
      #pragma unroll
      for (int r = 0; r < 4; ++r){
        const int n = n0 + nb*16 + quad*4 + r;
        const float v = acc[nb][r] + bp[n];
        g_VT[(((size_t)bb*H_ + (n>>5))*16 + (nr>>5))*1024 + (size_t)(n&31)*32 + (nr&31)] = f2b(v);
      }
  } else {
    #pragma unroll
    for (int k0 = 0; k0 < 256; k0 += 32){
      const float* ap = Ap + (size_t)arow*256 + k0 + quad*8;
      const v8s af = pack8(reinterpret_cast<const float4*>(ap)[0],
                           reinterpret_cast<const float4*>(ap)[1]);
      #pragma unroll
      for (int nb = 0; nb < 4; ++nb){
        const v8s wf = *reinterpret_cast<const v8s*>(&Wl[(nb*16+kl)*264 + k0 + quad*8]);
        acc[nb] = __builtin_amdgcn_mfma_f32_16x16x32_bf16(af, wf, acc[nb], 0, 0, 0);
      }
    }
    unsigned short* dst = z ? g_Kb : g_Qb;
    #pragma unroll
    for (int nb = 0; nb < 4; ++nb){
      const int n = n0 + nb*16 + kl;
      const float bias = bp[n];
      #pragma unroll
      for (int r = 0; r < 4; ++r){
        const int m = m0 + quad*4 + r;
        const float v = acc[nb][r] + bias;
        dst[(((size_t)(m>>9)*H_ + (n>>5))*N_ + (m&511))*DK_ + (n&31)] = f2b(v);
      }
    }
  }
}

// ---------------------------------------------------------------------------
// Dispatch 3: attention. 512 thr = 8 waves = 8 heads; one (b,qtile).
// k chunked 4x128, deferred softmax normalization -> <=128 regs -> 2 blocks/CU.
// ---------------------------------------------------------------------------
__global__ __launch_bounds__(512, 4) void attn_kernel(
    const int* __restrict__ mask, const float* __restrict__ bo,
    float* __restrict__ out)
{
  __shared__ unsigned short STl[16*520];    // 16.6 KB  ST[qrow][k] bf16 (padded)
  __shared__ unsigned short Pl[8*16*40];    // 10.2 KB  per-wave P chunk
  __shared__ unsigned short Xl[16*272];     //  8.7 KB  X[qrow][n] bf16
  const int bid = blockIdx.x;
  const int b  = bid & 15;                  // same-b -> same XCD (K/V L2 reuse)
  const int qt = bid >> 4;
  const int q0 = qt*16;
  const int t  = threadIdx.x;
  const int w  = t >> 6, lane = t & 63;
  const int kl = lane & 15, quad = lane >> 4;

  // ---- stage precomputed ST tile (16KB bf16, L2/L3-hot) into padded LDS ----
  {
    const int row = t >> 5;                 // 16 rows, 32 thr each
    const int c16 = (t & 31) * 16;
    const unsigned short* src = g_ST + ((size_t)(b*N_ + q0 + row))*N_ + c16;
    *reinterpret_cast<v8s*>(&STl[row*520 + c16])     = *reinterpret_cast<const v8s*>(src);
    *reinterpret_cast<v8s*>(&STl[row*520 + c16 + 8]) = *reinterpret_cast<const v8s*>(src + 8);
  }

  const int h = w;
  const size_t bh = (size_t)b*H_ + h;
  const float scale = 0.17677669529663687f;   // 1/sqrt(32)
  const unsigned short* Qp = g_Qb + (bh*N_ + q0)*DK_;
  const unsigned short* Kp = g_Kb + bh*N_*DK_;
  const unsigned short* Vp = g_VT + bh*(size_t)(N_*DK_);
  unsigned short* Plw = Pl + w*640;           // 16x40 per wave
  const int* mrow = mask + b*N_;
  const v8s aq = *reinterpret_cast<const v8s*>(Qp + (size_t)kl*DK_ + quad*8);
  const v4f vz = {0.f, 0.f, 0.f, 0.f};

  v4f oA0 = vz, oA1 = vz;     // attention PV (unnormalized)
  v4f oS0 = vz, oS1 = vz;     // ST PV (pre-scaled)
  float lsum[4] = {0.f, 0.f, 0.f, 0.f};

  __syncthreads();            // STl visible to all waves

  #pragma unroll 1
  for (int ch = 0; ch < 4; ++ch){
    const int k0 = ch*128;
    v4f acc[8];
    #pragma unroll
    for (int kb = 0; kb < 8; ++kb){
      const v8s bk = *reinterpret_cast<const v8s*>(Kp + (size_t)(k0 + kb*16 + kl)*DK_ + quad*8);
      acc[kb] = __builtin_amdgcn_mfma_f32_16x16x32_bf16(aq, bk, vz, 0, 0, 0);
    }
    #pragma unroll
    for (int kb = 0; kb < 8; ++kb){
      const bool valid = (mrow[k0 + kb*16 + kl] != 0);
      #pragma unroll
      for (int r = 0; r < 4; ++r){
        const float e = valid ? __expf(acc[kb][r]*scale) : 0.f;
        acc[kb][r] = e;               // raw exp; normalize at the end
        lsum[r] += e;
      }
    }
    #pragma unroll
    for (int cc = 0; cc < 4; ++cc){
      #pragma unroll
      for (int r = 0; r < 4; ++r){
        Plw[(quad*4 + r)*40 + kl]      = f2b(acc[2*cc    ][r]);
        Plw[(quad*4 + r)*40 + 16 + kl] = f2b(acc[2*cc + 1][r]);
      }
      const int kk = k0 + cc*32;
      // wave-private region: same-wave write->read ordered via lgkmcnt
      const v8s bp  = *reinterpret_cast<const v8s*>(&Plw[kl*40 + quad*8]);
      const v8s bst = *reinterpret_cast<const v8s*>(&STl[kl*520 + kk + quad*8]);
      const v8s av0 = *reinterpret_cast<const v8s*>(Vp + (size_t)(kk + kl)*32 + quad*8);
      const v8s av1 = *reinterpret_cast<const v8s*>(Vp + (size_t)(kk + 16 + kl)*32 + quad*8);
      oA0 = __builtin_amdgcn_mfma_f32_16x16x32_bf16(av0, bp,  oA0, 0, 0, 0);
      oS0 = __builtin_amdgcn_mfma_f32_16x16x32_bf16(av0, bst, oS0, 0, 0, 0);
      oA1 = __builtin_amdgcn_mfma_f32_16x16x32_bf16(av1, bp,  oA1, 0, 0, 0);
      oS1 = __builtin_amdgcn_mfma_f32_16x16x32_bf16(av1, bst, oS1, 0, 0, 0);
    }
  }

  // softmax denominators: lsum[r] = full-row sum for q = quad*4+r
  #pragma unroll
  for (int r = 0; r < 4; ++r)
    #pragma unroll
    for (int o = 1; o < 16; o <<= 1) lsum[r] += __shfl_xor(lsum[r], o, 64);
  // redistribute: this lane's O columns are q = kl; fetch lsum[kl&3] from quad kl>>2
  const float s01 = (kl & 1) ? lsum[1] : lsum[0];
  const float s23 = (kl & 1) ? lsum[3] : lsum[2];
  const float sv  = (kl & 2) ? s23 : s01;
  float inv = __shfl(sv, ((kl >> 2) << 4) | (kl & 3), 64);
  inv = (inv > 0.f) ? 0.3f / inv : 0.f;

  // X[qrow=kl][n = h*32 + d'] bf16 into LDS (lane holds O^T[d'][q=kl])
  unsigned short* xr = Xl + kl*272 + h*32;
  #pragma unroll
  for (int r = 0; r < 4; ++r){
    xr[     quad*4 + r] = f2b(oA0[r]*inv + oS0[r]);
    xr[16 + quad*4 + r] = f2b(oA1[r]*inv + oS1[r]);
  }
  __syncthreads();

  // ---- Phase C: out = X @ Wo^T + bo, wave w -> n in [w*32, w*32+32) ----
  {
    const int n0 = w*32;
    v4f a2[2];
    a2[0] = vz; a2[1] = vz;
    #pragma unroll
    for (int k0 = 0; k0 < 256; k0 += 32){
      const v8s af = *reinterpret_cast<const v8s*>(&Xl[kl*272 + k0 + quad*8]);
      #pragma unroll
      for (int nb = 0; nb < 2; ++nb){
        const v8s wf = *reinterpret_cast<const v8s*>(
            g_WoB + (size_t)(k0 >> 5)*8192 + (size_t)(n0 + nb*16 + kl)*32 + quad*8);
        a2[nb] = __builtin_amdgcn_mfma_f32_16x16x32_bf16(af, wf, a2[nb], 0, 0, 0);
      }
    }
    #pragma unroll
    for (int nb = 0; nb < 2; ++nb){
      const int n = n0 + nb*16 + kl;
      const float bias = bo[n];
      #pragma unroll
      for (int r = 0; r < 4; ++r)
        out[((size_t)(b*N_ + q0 + quad*4 + r))*256 + n] = a2[nb][r] + bias;
    }
  }
}

extern "C" void kernel_launch(void* const* d_in, const int* in_sizes, int n_in,
                              void* d_out, int out_size, void* d_ws, size_t ws_size,
                              hipStream_t stream)
{
  const float* query = (const float*)d_in[0];
  const float* key_  = (const float*)d_in[1];
  const float* value = (const float*)d_in[2];
  const float* adjm  = (const float*)d_in[3];
  const float* dist  = (const float*)d_in[4];
  // d_in[5] = edges_att (unused)
  const int*   mask  = (const int*)d_in[6];
  const float* Wq = (const float*)d_in[7];  const float* bq = (const float*)d_in[8];
  const float* Wk = (const float*)d_in[9];  const float* bk = (const float*)d_in[10];
  const float* Wv = (const float*)d_in[11]; const float* bv = (const float*)d_in[12];
  const float* Wo = (const float*)d_in[13]; const float* bo = (const float*)d_in[14];

  prep_w<<<256, 256, 0, stream>>>(Wq, Wk, Wv, Wo);
  st_kernel<<<512, 512, 0, stream>>>(dist, adjm, mask);
  qkv_gemm<<<1536, 256, 0, stream>>>(query, key_, value, bq, bk, bv);
  attn_kernel<<<512, 512, 0, stream>>>(mask, bo, (float*)d_out);
}

// Round 5
// 163.653 us; speedup vs baseline: 1.4001x; 1.0085x over previous
//
#include <hip/hip_runtime.h>
#include <cstdint>
#include <cstddef>

#define B_  16
#define N_  512
#define D_  256
#define H_  8
#define DK_ 32
// Round 13: attn latency-chain fix + dispatch merge.
//  1) st_prep (544 blk x 512 thr): bid<512 ST build (unchanged math);
//     bid>=512: W->bf16 conversion (was separate prep_w dispatch).
//  2) qkv_gemm (1536 blk x 256 thr): unchanged round-12 structure.
//  3) attn_kernel: per-128-key chunk, batch all 32 P ds_writes -> ONE lgkm
//     drain (was 4 write->drain->read cycles); prefetch 8 V fragments and
//     8 mask words into regs before the exp phase (global latency hidden
//     under VALU). P buffer 16x136/wave. LDS 58.8KB, still 2 blk/CU.

#define QKV_ELEMS 2097152   // B*N*D

__device__ __align__(16) unsigned short g_Qb[QKV_ELEMS];   // [B,H,N,DK] bf16
__device__ __align__(16) unsigned short g_Kb[QKV_ELEMS];   // [B,H,N,DK] bf16
__device__ __align__(16) unsigned short g_VT[QKV_ELEMS];   // [B,H,tokblk,DK,tok32] bf16
__device__ __align__(16) unsigned short g_WqB[D_*D_];      // Wq bf16 [n][k]
__device__ __align__(16) unsigned short g_WkB[D_*D_];      // Wk bf16 [n][k]
__device__ __align__(16) unsigned short g_WvB[D_*D_];      // Wv bf16 [n][k]
__device__ __align__(16) unsigned short g_WoB[D_*D_];      // Wo bf16 [k>>5][n][k&31]
__device__ __align__(16) unsigned short g_ST[B_*N_*N_];    // blended dist/adj bf16 [b][q][k]

typedef short v8s __attribute__((ext_vector_type(8)));
typedef float v4f __attribute__((ext_vector_type(4)));

__device__ __forceinline__ unsigned short f2b(float f){
  unsigned int x;
  __builtin_memcpy(&x, &f, 4);
  x = x + 0x7FFFu + ((x >> 16) & 1u);   // round-to-nearest-even
  return (unsigned short)(x >> 16);
}
__device__ __forceinline__ v8s pack8(const float4 a, const float4 b){
  v8s o;
  o[0]=(short)f2b(a.x); o[1]=(short)f2b(a.y); o[2]=(short)f2b(a.z); o[3]=(short)f2b(a.w);
  o[4]=(short)f2b(b.x); o[5]=(short)f2b(b.y); o[6]=(short)f2b(b.z); o[7]=(short)f2b(b.w);
  return o;
}

// ---------------------------------------------------------------------------
// Dispatch 0: bid<512: ST build (16 q-rows x 512 k per block, no LDS).
//             bid>=512 (32 blocks): W fp32->bf16 conversion.
// ---------------------------------------------------------------------------
__global__ __launch_bounds__(512) void st_prep(
    const float* __restrict__ dist, const float* __restrict__ adjm,
    const int* __restrict__ mask,
    const float* __restrict__ Wq, const float* __restrict__ Wk,
    const float* __restrict__ Wv, const float* __restrict__ Wo)
{
  const int bid = blockIdx.x;
  const int t = threadIdx.x;

  if (bid >= 512){   // ---- W conversion: 32 blk x 512 thr x 4 float4 ----
    const int tid = (bid - 512)*512 + t;
    #pragma unroll
    for (int u = 0; u < 4; ++u){
      const int i4 = tid*4 + u;          // float4 index
      const int i  = i4*4;               // float index (16-aligned per thread)
      const int z  = i >> 16;            // 0:Wq 1:Wk 2:Wv 3:Wo
      const int lo = i & 65535;
      const float* src = (z==0)?Wq:(z==1)?Wk:(z==2)?Wv:Wo;
      const float4 f = *reinterpret_cast<const float4*>(src + lo);
      ushort4 o4;
      o4.x=f2b(f.x); o4.y=f2b(f.y); o4.z=f2b(f.z); o4.w=f2b(f.w);
      if (z < 3){
        unsigned short* dst = (z==0)?g_WqB:(z==1)?g_WkB:g_WvB;
        *reinterpret_cast<ushort4*>(dst + lo) = o4;
      } else {
        const int n = lo >> 8, k = lo & 255;
        *reinterpret_cast<ushort4*>(g_WoB + ((size_t)(k >> 5))*8192 + (size_t)n*32 + (k & 31)) = o4;
      }
    }
    return;
  }

  // ---- ST build ----
  const int b = bid & 15, qt = bid >> 4, q0 = qt*16;   // same-b -> same XCD
  const int row = t >> 5, seg = t & 31;
  const size_t roff = ((size_t)(b*N_ + q0 + row))*N_ + seg*16;
  const float* dp = dist + roff;
  const float* ap = adjm + roff;
  const int*   mp = mask + b*N_ + seg*16;
  // all 12 loads issued back-to-back (MLP)
  const float4 d0 = reinterpret_cast<const float4*>(dp)[0];
  const float4 d1 = reinterpret_cast<const float4*>(dp)[1];
  const float4 d2 = reinterpret_cast<const float4*>(dp)[2];
  const float4 d3 = reinterpret_cast<const float4*>(dp)[3];
  const float4 a0 = reinterpret_cast<const float4*>(ap)[0];
  const float4 a1 = reinterpret_cast<const float4*>(ap)[1];
  const float4 a2 = reinterpret_cast<const float4*>(ap)[2];
  const float4 a3 = reinterpret_cast<const float4*>(ap)[3];
  const int4   m0 = reinterpret_cast<const int4*>(mp)[0];
  const int4   m1 = reinterpret_cast<const int4*>(mp)[1];
  const int4   m2 = reinterpret_cast<const int4*>(mp)[2];
  const int4   m3 = reinterpret_cast<const int4*>(mp)[3];

  float ev[16], av[16];
  #define ST_STEP(i, d4, a4, m4) \
    ev[i+0] = m4.x ? __expf(-d4.x) : 0.f;  av[i+0] = a4.x; \
    ev[i+1] = m4.y ? __expf(-d4.y) : 0.f;  av[i+1] = a4.y; \
    ev[i+2] = m4.z ? __expf(-d4.z) : 0.f;  av[i+2] = a4.z; \
    ev[i+3] = m4.w ? __expf(-d4.w) : 0.f;  av[i+3] = a4.w;
  ST_STEP(0,  d0, a0, m0)
  ST_STEP(4,  d1, a1, m1)
  ST_STEP(8,  d2, a2, m2)
  ST_STEP(12, d3, a3, m3)
  #undef ST_STEP
  float lz = 0.f, la = 0.f;
  #pragma unroll
  for (int i = 0; i < 16; ++i){ lz += ev[i]; la += av[i]; }
  #pragma unroll
  for (int o = 1; o < 32; o <<= 1){   // 32 lanes share a row (bits 0..4)
    lz += __shfl_xor(lz, o, 64);
    la += __shfl_xor(la, o, 64);
  }
  const float c0 = (lz > 0.f) ? 0.3f / lz : 0.f;
  const float c1 = 0.4f / (la + 1e-6f);
  v8s s0, s1;
  #pragma unroll
  for (int i = 0; i < 8; ++i){
    s0[i] = (short)f2b(ev[i]*c0   + av[i]*c1);
    s1[i] = (short)f2b(ev[8+i]*c0 + av[8+i]*c1);
  }
  *reinterpret_cast<v8s*>(g_ST + roff)     = s0;
  *reinterpret_cast<v8s*>(g_ST + roff + 8) = s1;
}

// ---------------------------------------------------------------------------
// Dispatch 1: QKV GEMM (proven LDS-staged structure, bf16 W source).
// C[m][n] = sum_k A[m][k]*W[n][k] + b[n], M=8192, N=K=256.
// ---------------------------------------------------------------------------
__global__ __launch_bounds__(256) void qkv_gemm(
    const float* __restrict__ query, const float* __restrict__ key_,
    const float* __restrict__ value,
    const float* __restrict__ bq, const float* __restrict__ bk,
    const float* __restrict__ bv)
{
  __shared__ unsigned short Wl[64*264];   // 33.8 KB
  const int bid = blockIdx.x;
  const int t   = threadIdx.x;
  const int z  = bid >> 9;                 // 0:Q 1:K 2:V
  const int rr = bid & 511;
  const int mt = rr >> 2, nt = rr & 3;     // nt fastest: 4 consecutive blocks share A tile
  const float* Ap = (z==0) ? query : (z==1) ? key_ : value;
  const unsigned short* WB = (z==0) ? g_WqB : (z==1) ? g_WkB : g_WvB;
  const float* bp = (z==0) ? bq : (z==1) ? bk : bv;
  const int w = t >> 6, lane = t & 63, kl = lane & 15, quad = lane >> 4;
  const int m0 = mt*64 + w*16;
  const int n0 = nt*64;

  {   // stage bf16 W tile [n0..n0+63][0..255]
    const int row = t >> 2;
    const int ks  = (t & 3) * 64;
    const unsigned short* src = WB + (size_t)(n0+row)*256 + ks;
    unsigned short* dst = Wl + row*264 + ks;
    #pragma unroll
    for (int u = 0; u < 8; ++u)
      *reinterpret_cast<v8s*>(dst + u*8) = *reinterpret_cast<const v8s*>(src + u*8);
  }
  __syncthreads();

  v4f acc[4];
  #pragma unroll
  for (int nb = 0; nb < 4; ++nb) acc[nb] = (v4f){0.f,0.f,0.f,0.f};
  const int arow = m0 + kl;

  if (z == 2){
    #pragma unroll
    for (int k0 = 0; k0 < 256; k0 += 32){
      const float* ap = Ap + (size_t)arow*256 + k0 + quad*8;
      const v8s af = pack8(reinterpret_cast<const float4*>(ap)[0],
                           reinterpret_cast<const float4*>(ap)[1]);
      #pragma unroll
      for (int nb = 0; nb < 4; ++nb){
        const v8s wf = *reinterpret_cast<const v8s*>(&Wl[(nb*16+kl)*264 + k0 + quad*8]);
        acc[nb] = __builtin_amdgcn_mfma_f32_16x16x32_bf16(wf, af, acc[nb], 0, 0, 0);
      }
    }
    // D[n][tok]; tile-interleaved store: [bb,h, tokblk, dk, tok&31]
    const int tok = m0 + kl, bb = tok >> 9, nr = tok & 511;
    #pragma unroll
    for (int nb = 0; nb < 4; ++nb)
      #pragma unroll
      for (int r = 0; r < 4; ++r){
        const int n = n0 + nb*16 + quad*4 + r;
        const float v = acc[nb][r] + bp[n];
        g_VT[(((size_t)bb*H_ + (n>>5))*16 + (nr>>5))*1024 + (size_t)(n&31)*32 + (nr&31)] = f2b(v);
      }
  } else {
    #pragma unroll
    for (int k0 = 0; k0 < 256; k0 += 32){
      const float* ap = Ap + (size_t)arow*256 + k0 + quad*8;
      const v8s af = pack8(reinterpret_cast<const float4*>(ap)[0],
                           reinterpret_cast<const float4*>(ap)[1]);
      #pragma unroll
      for (int nb = 0; nb < 4; ++nb){
        const v8s wf = *reinterpret_cast<const v8s*>(&Wl[(nb*16+kl)*264 + k0 + quad*8]);
        acc[nb] = __builtin_amdgcn_mfma_f32_16x16x32_bf16(af, wf, acc[nb], 0, 0, 0);
      }
    }
    unsigned short* dst = z ? g_Kb : g_Qb;
    #pragma unroll
    for (int nb = 0; nb < 4; ++nb){
      const int n = n0 + nb*16 + kl;
      const float bias = bp[n];
      #pragma unroll
      for (int r = 0; r < 4; ++r){
        const int m = m0 + quad*4 + r;
        const float v = acc[nb][r] + bias;
        dst[(((size_t)(m>>9)*H_ + (n>>5))*N_ + (m&511))*DK_ + (n&31)] = f2b(v);
      }
    }
  }
}

// ---------------------------------------------------------------------------
// Dispatch 2: attention. 512 thr = 8 waves = 8 heads; one (b,qtile).
// Per-128-key chunk: batched P writes (one lgkm drain), V+mask prefetched.
// ---------------------------------------------------------------------------
__global__ __launch_bounds__(512, 4) void attn_kernel(
    const int* __restrict__ mask, const float* __restrict__ bo,
    float* __restrict__ out)
{
  __shared__ unsigned short STl[16*520];    // 16.6 KB  ST[qrow][k] bf16 (padded)
  __shared__ unsigned short Pl[8*16*136];   // 34.0 KB  per-wave P chunk (16x128 +pad)
  __shared__ unsigned short Xl[16*272];     //  8.7 KB  X[qrow][n] bf16
  const int bid = blockIdx.x;
  const int b  = bid & 15;                  // same-b -> same XCD (K/V L2 reuse)
  const int qt = bid >> 4;
  const int q0 = qt*16;
  const int t  = threadIdx.x;
  const int w  = t >> 6, lane = t & 63;
  const int kl = lane & 15, quad = lane >> 4;

  // ---- stage precomputed ST tile (16KB bf16, L2/L3-hot) into padded LDS ----
  {
    const int row = t >> 5;                 // 16 rows, 32 thr each
    const int c16 = (t & 31) * 16;
    const unsigned short* src = g_ST + ((size_t)(b*N_ + q0 + row))*N_ + c16;
    *reinterpret_cast<v8s*>(&STl[row*520 + c16])     = *reinterpret_cast<const v8s*>(src);
    *reinterpret_cast<v8s*>(&STl[row*520 + c16 + 8]) = *reinterpret_cast<const v8s*>(src + 8);
  }

  const int h = w;
  const size_t bh = (size_t)b*H_ + h;
  const float scale = 0.17677669529663687f;   // 1/sqrt(32)
  const unsigned short* Qp = g_Qb + (bh*N_ + q0)*DK_;
  const unsigned short* Kp = g_Kb + bh*N_*DK_;
  const unsigned short* Vp = g_VT + bh*(size_t)(N_*DK_);
  unsigned short* Plw = Pl + w*2176;          // 16x136 per wave
  const int* mrow = mask + b*N_;
  const v8s aq = *reinterpret_cast<const v8s*>(Qp + (size_t)kl*DK_ + quad*8);
  const v4f vz = {0.f, 0.f, 0.f, 0.f};

  v4f oA0 = vz, oA1 = vz;     // attention PV (unnormalized)
  v4f oS0 = vz, oS1 = vz;     // ST PV (pre-scaled)
  float lsum[4] = {0.f, 0.f, 0.f, 0.f};

  __syncthreads();            // STl visible to all waves

  #pragma unroll 1
  for (int ch = 0; ch < 4; ++ch){
    const int k0 = ch*128;
    // QK^T for 128 keys
    v4f acc[8];
    #pragma unroll
    for (int kb = 0; kb < 8; ++kb){
      const v8s bk = *reinterpret_cast<const v8s*>(Kp + (size_t)(k0 + kb*16 + kl)*DK_ + quad*8);
      acc[kb] = __builtin_amdgcn_mfma_f32_16x16x32_bf16(aq, bk, vz, 0, 0, 0);
    }
    // prefetch V fragments + mask words (global) before the VALU exp phase
    v8s av[8];
    int mk[8];
    #pragma unroll
    for (int cc = 0; cc < 4; ++cc){
      const int kk = k0 + cc*32;
      av[2*cc]   = *reinterpret_cast<const v8s*>(Vp + (size_t)(kk + kl)*32 + quad*8);
      av[2*cc+1] = *reinterpret_cast<const v8s*>(Vp + (size_t)(kk + 16 + kl)*32 + quad*8);
    }
    #pragma unroll
    for (int kb = 0; kb < 8; ++kb) mk[kb] = mrow[k0 + kb*16 + kl];
    // exp (raw, normalize at the end)
    #pragma unroll
    for (int kb = 0; kb < 8; ++kb){
      const bool valid = (mk[kb] != 0);
      #pragma unroll
      for (int r = 0; r < 4; ++r){
        const float e = valid ? __expf(acc[kb][r]*scale) : 0.f;
        acc[kb][r] = e;
        lsum[r] += e;
      }
    }
    // batched P writes: ONE lgkm drain for the whole 128-key chunk
    #pragma unroll
    for (int kb = 0; kb < 8; ++kb)
      #pragma unroll
      for (int r = 0; r < 4; ++r)
        Plw[(quad*4 + r)*136 + kb*16 + kl] = f2b(acc[kb][r]);
    // PV: pure LDS reads + MFMA, V already in regs
    #pragma unroll
    for (int cc = 0; cc < 4; ++cc){
      const int kk = k0 + cc*32;
      const v8s bp  = *reinterpret_cast<const v8s*>(&Plw[kl*136 + cc*32 + quad*8]);
      const v8s bst = *reinterpret_cast<const v8s*>(&STl[kl*520 + kk + quad*8]);
      oA0 = __builtin_amdgcn_mfma_f32_16x16x32_bf16(av[2*cc],   bp,  oA0, 0, 0, 0);
      oS0 = __builtin_amdgcn_mfma_f32_16x16x32_bf16(av[2*cc],   bst, oS0, 0, 0, 0);
      oA1 = __builtin_amdgcn_mfma_f32_16x16x32_bf16(av[2*cc+1], bp,  oA1, 0, 0, 0);
      oS1 = __builtin_amdgcn_mfma_f32_16x16x32_bf16(av[2*cc+1], bst, oS1, 0, 0, 0);
    }
  }

  // softmax denominators: lsum[r] = full-row sum for q = quad*4+r
  #pragma unroll
  for (int r = 0; r < 4; ++r)
    #pragma unroll
    for (int o = 1; o < 16; o <<= 1) lsum[r] += __shfl_xor(lsum[r], o, 64);
  // redistribute: this lane's O columns are q = kl; fetch lsum[kl&3] from quad kl>>2
  const float s01 = (kl & 1) ? lsum[1] : lsum[0];
  const float s23 = (kl & 1) ? lsum[3] : lsum[2];
  const float sv  = (kl & 2) ? s23 : s01;
  float inv = __shfl(sv, ((kl >> 2) << 4) | (kl & 3), 64);
  inv = (inv > 0.f) ? 0.3f / inv : 0.f;

  // X[qrow=kl][n = h*32 + d'] bf16 into LDS (lane holds O^T[d'][q=kl])
  unsigned short* xr = Xl + kl*272 + h*32;
  #pragma unroll
  for (int r = 0; r < 4; ++r){
    xr[     quad*4 + r] = f2b(oA0[r]*inv + oS0[r]);
    xr[16 + quad*4 + r] = f2b(oA1[r]*inv + oS1[r]);
  }
  __syncthreads();

  // ---- Phase C: out = X @ Wo^T + bo, wave w -> n in [w*32, w*32+32) ----
  {
    const int n0 = w*32;
    v4f a2[2];
    a2[0] = vz; a2[1] = vz;
    #pragma unroll
    for (int k0 = 0; k0 < 256; k0 += 32){
      const v8s af = *reinterpret_cast<const v8s*>(&Xl[kl*272 + k0 + quad*8]);
      #pragma unroll
      for (int nb = 0; nb < 2; ++nb){
        const v8s wf = *reinterpret_cast<const v8s*>(
            g_WoB + (size_t)(k0 >> 5)*8192 + (size_t)(n0 + nb*16 + kl)*32 + quad*8);
        a2[nb] = __builtin_amdgcn_mfma_f32_16x16x32_bf16(af, wf, a2[nb], 0, 0, 0);
      }
    }
    #pragma unroll
    for (int nb = 0; nb < 2; ++nb){
      const int n = n0 + nb*16 + kl;
      const float bias = bo[n];
      #pragma unroll
      for (int r = 0; r < 4; ++r)
        out[((size_t)(b*N_ + q0 + quad*4 + r))*256 + n] = a2[nb][r] + bias;
    }
  }
}

extern "C" void kernel_launch(void* const* d_in, const int* in_sizes, int n_in,
                              void* d_out, int out_size, void* d_ws, size_t ws_size,
                              hipStream_t stream)
{
  const float* query = (const float*)d_in[0];
  const float* key_  = (const float*)d_in[1];
  const float* value = (const float*)d_in[2];
  const float* adjm  = (const float*)d_in[3];
  const float* dist  = (const float*)d_in[4];
  // d_in[5] = edges_att (unused)
  const int*   mask  = (const int*)d_in[6];
  const float* Wq = (const float*)d_in[7];  const float* bq = (const float*)d_in[8];
  const float* Wk = (const float*)d_in[9];  const float* bk = (const float*)d_in[10];
  const float* Wv = (const float*)d_in[11]; const float* bv = (const float*)d_in[12];
  const float* Wo = (const float*)d_in[13]; const float* bo = (const float*)d_in[14];

  st_prep<<<544, 512, 0, stream>>>(dist, adjm, mask, Wq, Wk, Wv, Wo);
  qkv_gemm<<<1536, 256, 0, stream>>>(query, key_, value, bq, bk, bv);
  attn_kernel<<<512, 512, 0, stream>>>(mask, bo, (float*)d_out);
}